// Round 17
// baseline (13.317 us; speedup 1.0000x reference)
//
#include <hip/hip_runtime.h>
#include <math.h>

#define BS 4
#define CH 256
#define XD 1024
#define N 128
#define NP 8128
#define NSTRIP 32              // column-groups of 4 per batch
#define STRIPBLK (BS * NSTRIP) // 128 strip blocks
#define NPASSBLK 256           // pass blocks, 4 rows each
#define TWO_PI_F 6.283185307179586f
#define PADR 66                // u32 row stride for 64 ch-pairs (+2 pad): banks (2*dim+4*cq)%32

typedef __fp16 h2v __attribute__((ext_vector_type(2)));

__device__ __forceinline__ h2v u2h(unsigned u) {
  union { unsigned u; h2v h; } c; c.u = u; return c.h;
}
__device__ __forceinline__ unsigned h2u(h2v h) {
  union { unsigned u; h2v h; } c; c.h = h; return c.u;
}

// ---------------------------------------------------------------------------
// SINGLE kernel, 384 blocks x 256 threads, zero cross-block communication.
//
// Math: v_new[j]/x_new[j] depend only on COLUMN j's mask bits, and
// mask[i,j] > 0.5 requires u_x = exp(-x_r) > 0.5 (since v_r/v_r_max <= 1),
// i.e. x_r^2 < ln(2)^2 -- a purely x-local test. So a block owning columns J
// that verifies x_r^2 >= threshold for all (i, J) may write its columns with
// the exact no-collision closed form out = x + 0.5*a, independent of v_r_max.
//
//  blocks [0,128): strip role. (b, g) owns kinetic columns [4g,4g+4) of
//    batch b. Stages x-dims as f16 pairs (2 channel-halves), dot2-computes
//    x_r^2 for all 128 x 4 pairs, predicate = any(i!=j && x_r^2 < 2.0)
//    [conservative vs 0.48: f16 margin]. Fast path (always, this data):
//    write 4 columns x 256 channels = x + 0.5*a. Slow path (never): exact
//    f32 self-contained recompute (own v_r_max over all pairs, own column
//    masks, own fixup) -- slow but correct, columns exclusively owned.
//  blocks [128,384): pass role. 4 rows each, writes ONLY non-dims positions
//    (nibble mask; all-dims quads skipped, mixed quads scalar). Disjoint
//    from strip writes -> no ordering needed anywhere.
// ---------------------------------------------------------------------------
__global__ __launch_bounds__(256) void k_all(
    const float* __restrict__ x, const float* __restrict__ a,
    const float* __restrict__ ru, const int* __restrict__ dims,
    float* __restrict__ out) {
  int bid = blockIdx.x, t = threadIdx.x;
  __shared__ unsigned sX[N][PADR];   // f16-pair packed x-dims, one ch-half
  __shared__ unsigned inset[XD / 32];
  __shared__ int dsh[N];
  __shared__ int flg[2];             // [0]=dims contiguous, [1]=candidate
  __shared__ float red[256];
  __shared__ unsigned maskb[4][4];   // slow path: 4 cols x 128 mask bits
  __shared__ float vrcol[4][N];      // slow path: vr for my 4 columns

  if (bid >= STRIPBLK) {
    // ---------------- pass role: non-dims positions only ----------------
    int pb = bid - STRIPBLK;  // 0..255
    if (t < XD / 32) inset[t] = 0u;
    __syncthreads();
    if (t < N) atomicOr(&inset[dims[t] >> 5], 1u << (dims[t] & 31));
    __syncthreads();
    int row0 = pb << 2;
#pragma unroll
    for (int r = 0; r < 4; ++r) {
      int row = row0 + r;
      const float4* x4 = (const float4*)(x + (size_t)row * XD);
      const float4* a4 = (const float4*)(a + (size_t)row * XD);
      float4* o4 = (float4*)(out + (size_t)row * XD);
      int e = t;  // float4 index 0..255
      unsigned nib = (inset[e >> 3] >> ((e & 7) * 4)) & 0xFu;
      if (nib == 0u) {  // pure non-dims quad
        float4 xv = x4[e], av = a4[e];
        o4[e] = make_float4(xv.x + av.x, xv.y + av.y, xv.z + av.z, xv.w + av.w);
      } else if (nib != 0xFu) {  // mixed quad (general dims)
#pragma unroll
        for (int c2 = 0; c2 < 4; ++c2) {
          if (!(nib & (1u << c2))) {
            size_t off = (size_t)row * XD + 4 * e + c2;
            out[off] = x[off] + a[off];
          }
        }
      }  // nib==0xF: all-dims quad, strip-owned
    }
    return;
  }

  // ---------------- strip role ----------------
  int b = bid / NSTRIP, g = bid % NSTRIP;
  if (t == 0) { flg[0] = 1; flg[1] = 0; }
  __syncthreads();
  if (t < N) {
    int d = dims[t];
    dsh[t] = d;
    if (d != t) atomicAnd(&flg[0], 0);
  }
  __syncthreads();
  int contig = flg[0];
  const float* xb = x + (size_t)b * CH * XD;

  // predicate over 2 channel-halves: pairs (i, j=4g+(t&3)), i = t>>2, +64
  int jj = 4 * g + (t & 3);
  int i1 = t >> 2, i2 = i1 + 64;
  float acc1 = 0.f, acc2 = 0.f;
  for (int h = 0; h < 2; ++h) {
    __syncthreads();  // protect previous half's readers
    if (contig) {
      for (int u = t; u < 64 * 32; u += 256) {  // (ch-pair-local, dim-quad)
        int cpl = u >> 5, q = u & 31;
        int cp = (h << 6) + cpl;
        float4 f0 = *(const float4*)&xb[(size_t)(2 * cp) * XD + 4 * q];
        float4 f1 = *(const float4*)&xb[(size_t)(2 * cp + 1) * XD + 4 * q];
        sX[4 * q + 0][cpl] = h2u(__builtin_amdgcn_cvt_pkrtz(f0.x, f1.x));
        sX[4 * q + 1][cpl] = h2u(__builtin_amdgcn_cvt_pkrtz(f0.y, f1.y));
        sX[4 * q + 2][cpl] = h2u(__builtin_amdgcn_cvt_pkrtz(f0.z, f1.z));
        sX[4 * q + 3][cpl] = h2u(__builtin_amdgcn_cvt_pkrtz(f0.w, f1.w));
      }
    } else {  // general gather: 2 threads per dim, 32 ch-pairs each
      int dd = t & 127, sub = t >> 7;
      int d = dsh[dd];
      for (int m = 0; m < 32; ++m) {
        int cpl = sub * 32 + m;
        int cp = (h << 6) + cpl;
        float f0 = xb[(size_t)(2 * cp) * XD + d];
        float f1 = xb[(size_t)(2 * cp + 1) * XD + d];
        sX[dd][cpl] = h2u(__builtin_amdgcn_cvt_pkrtz(f0, f1));
      }
    }
    __syncthreads();
#pragma unroll 8
    for (int cq = 0; cq < 16; ++cq) {
      uint4 xj = *(const uint4*)&sX[jj][cq * 4];
      uint4 u1 = *(const uint4*)&sX[i1][cq * 4];
      uint4 u2 = *(const uint4*)&sX[i2][cq * 4];
      h2v d;
      d = u2h(u1.x) - u2h(xj.x); acc1 = __builtin_amdgcn_fdot2(d, d, acc1, false);
      d = u2h(u1.y) - u2h(xj.y); acc1 = __builtin_amdgcn_fdot2(d, d, acc1, false);
      d = u2h(u1.z) - u2h(xj.z); acc1 = __builtin_amdgcn_fdot2(d, d, acc1, false);
      d = u2h(u1.w) - u2h(xj.w); acc1 = __builtin_amdgcn_fdot2(d, d, acc1, false);
      d = u2h(u2.x) - u2h(xj.x); acc2 = __builtin_amdgcn_fdot2(d, d, acc2, false);
      d = u2h(u2.y) - u2h(xj.y); acc2 = __builtin_amdgcn_fdot2(d, d, acc2, false);
      d = u2h(u2.z) - u2h(xj.z); acc2 = __builtin_amdgcn_fdot2(d, d, acc2, false);
      d = u2h(u2.w) - u2h(xj.w); acc2 = __builtin_amdgcn_fdot2(d, d, acc2, false);
    }
  }
  // candidate: u_x > 0.5 possible, i.e. x_r^2 < ln2^2 (=0.48; 2.0 = f16 margin)
  bool cand = ((i1 != jj) && (acc1 < 2.0f)) || ((i2 != jj) && (acc2 < 2.0f));
  if (__any(cand)) {
    if ((t & 63) == 0) atomicOr(&flg[1], 1);
  }
  __syncthreads();

  if (!flg[1]) {
    // ---- fast path: my 4 columns are provably collision-free ----
    int row = (b << 8) + t;  // one channel-row per thread
    if (contig) {
      const float4* x4 = (const float4*)(x + (size_t)row * XD);
      const float4* a4 = (const float4*)(a + (size_t)row * XD);
      float4 xv = x4[g], av = a4[g];
      ((float4*)(out + (size_t)row * XD))[g] =
          make_float4(fmaf(0.5f, av.x, xv.x), fmaf(0.5f, av.y, xv.y),
                      fmaf(0.5f, av.z, xv.z), fmaf(0.5f, av.w, xv.w));
    } else {
#pragma unroll
      for (int k = 0; k < 4; ++k) {
        size_t off = (size_t)row * XD + dsh[4 * g + k];
        out[off] = fmaf(0.5f, a[off], x[off]);
      }
    }
    return;
  }

  // ---- slow path: exact f32, fully self-contained (never taken here) ----
  const float* ab = a + (size_t)b * CH * XD;
  // 1) v_r_max over all upper-triangle pairs of batch b (global reads, f32)
  float vmx = 0.f;
  for (int cell = t; cell < N * N; cell += 256) {
    int i = cell >> 7, j = cell & 127;
    if (i < j) {
      int di = dsh[i], dj = dsh[j];
      float s = 0.f;
      for (int c = 0; c < CH; ++c) {
        float dv = ab[(size_t)c * XD + di] - ab[(size_t)c * XD + dj];
        s = fmaf(dv, dv, s);
      }
      vmx = fmaxf(vmx, s);
    }
  }
  red[t] = vmx;
  __syncthreads();
  for (int s2 = 128; s2 > 0; s2 >>= 1) {
    if (t < s2) red[t] = fmaxf(red[t], red[t + s2]);
    __syncthreads();
  }
  float vrmax = sqrtf(red[0]);
  float inv = vrmax > 0.f ? 1.f / vrmax : 0.f;  // vrmax==0 -> all-false mask

  // 2) exact masks + vr for my 4 columns
  if (t < 16) maskb[t >> 2][t & 3] = 0u;
  __syncthreads();
  for (int u = t; u < 4 * N; u += 256) {
    int kc = u >> 7, i = u & 127;
    int j = 4 * g + kc;
    int di = dsh[i], dj = dsh[j];
    float sx2 = 0.f, sv2 = 0.f;
    for (int c = 0; c < CH; ++c) {
      float dx = xb[(size_t)c * XD + di] - xb[(size_t)c * XD + dj];
      sx2 = fmaf(dx, dx, sx2);
      float dv = ab[(size_t)c * XD + di] - ab[(size_t)c * XD + dj];
      sv2 = fmaf(dv, dv, sv2);
    }
    float vr = sqrtf(sv2);
    float ux = expf(-sqrtf(sx2));
    vrcol[kc][i] = vr;
    if (vr * inv * ux > 0.5f) atomicOr(&maskb[kc][i >> 5], 1u << (i & 31));
  }
  __syncthreads();

  // 3) per-channel update for my 4 columns (thread = channel)
  {
    int c = t;
    int bc = (b << 8) + c;
    const float* rub = ru + (size_t)bc * NP;
#pragma unroll
    for (int kc = 0; kc < 4; ++kc) {
      int j = 4 * g + kc;
      int dj = dsh[j];
      float xxj = x[(size_t)bc * XD + dj];
      float vvj = a[(size_t)bc * XD + dj];
      float S = 0.f, sumV = 0.f, sumX = 0.f, R = 0.f;
      for (int w = 0; w < 4; ++w) {
        unsigned bits = maskb[kc][w];
        while (bits) {
          int i = (w << 5) + __ffs(bits) - 1;
          bits &= bits - 1;
          S += 1.f;
          int di = dsh[i];
          sumV += a[(size_t)bc * XD + di];
          sumX += x[(size_t)bc * XD + di];
          float vrv = vrcol[kc][i];
          int p;
          float sgn;
          if (i < j) {
            p = i * N - ((i * (i + 1)) >> 1) + (j - i - 1);
            sgn = 1.f;
          } else {
            p = j * N - ((j * (j + 1)) >> 1) + (i - j - 1);
            sgn = -1.f;
          }
          R += sgn * TWO_PI_F * vrv * rub[p];
        }
      }
      float v_new = vvj + 0.5f * S * vvj - 0.5f * sumV + R;
      float x_new = 0.5f * xxj + 0.5f * (xxj + sumX) / (S + 1.f) + 0.5f * v_new;
      out[(size_t)bc * XD + dj] = x_new;
    }
  }
}

extern "C" void kernel_launch(void* const* d_in, const int* in_sizes, int n_in,
                              void* d_out, int out_size, void* d_ws, size_t ws_size,
                              hipStream_t stream) {
  const float* x = (const float*)d_in[0];
  // d_in[1] = v : unused by the reference computation
  const float* a = (const float*)d_in[2];
  const float* ru = (const float*)d_in[3];
  const int* dims = (const int*)d_in[4];
  float* out = (float*)d_out;
  // d_ws unused: the column-local decomposition needs no workspace at all.

  k_all<<<STRIPBLK + NPASSBLK, 256, 0, stream>>>(x, a, ru, dims, out);
}

// Round 18
// 12.028 us; speedup vs baseline: 1.1072x; 1.1072x over previous
//
#include <hip/hip_runtime.h>
#include <math.h>

#define BS 4
#define CH 256
#define XD 1024
#define N 128
#define NP 8128
#define NTILE 36  // upper-triangle tiles of the 8x8 tile grid (ti<=tj)
#define NPASS 112 // passthrough blocks; 4*NTILE + NPASS = 256 = 1 block/CU
#define TWO_PI_F 6.283185307179586f
#define PADU 132  // LDS row stride in u32: 528 B, 16B-aligned, 2-way bank alias only

typedef __fp16 h2v __attribute__((ext_vector_type(2)));

__device__ __forceinline__ h2v u2h(unsigned u) {
  union { unsigned u; h2v h; } c; c.u = u; return c.h;
}
__device__ __forceinline__ unsigned h2u(h2v h) {
  union { unsigned u; h2v h; } c; c.h = h; return c.u;
}

// ---------------------------------------------------------------------------
// K1, grid 256 x 256 threads, two block roles (block-uniform branch):
//  blocks [0,144): one upper-triangle 16x16 pairdist tile each (f16 LDS +
//    v_dot2_f32_f16; vr/m symmetric -> ti<=tj only). NEW vs R16: when dims
//    is contiguous (runtime check; true here), staging is COALESCED float4
//    across dims -- 16 vector loads/thread vs 64 scalar gather loads.
//  blocks [144,256): the complete output write
//    out[e] = x[e] + (e in dims ? 0.5 : 1.0)*a[e]   (0.5 arm == exact
//    no-collision closed form x+0.5*a), concurrent on separate CUs.
// ---------------------------------------------------------------------------
__global__ __launch_bounds__(256) void k1_pair_pass(
    const float* __restrict__ x, const float* __restrict__ a,
    const int* __restrict__ dims,
    float* __restrict__ vrS, float* __restrict__ mS,
    float* __restrict__ pmaxV, float* __restrict__ pmaxM,
    float* __restrict__ out) {
  int bid = blockIdx.x;
  int t = threadIdx.x;
  __shared__ unsigned sXi[16][PADU], sXj[16][PADU], sAi[16][PADU], sAj[16][PADU];
  __shared__ unsigned inset[XD / 32];
  __shared__ float wred[16];
  __shared__ int flg;

  if (bid < BS * NTILE) {
    // ---------------- tile role ----------------
    int b = bid / NTILE, tt = bid % NTILE;
    int ti = 0;
    while (8 * (ti + 1) - ((ti + 1) * ti) / 2 <= tt) ++ti;  // uniform, <=8 iters
    int tj = ti + tt - (8 * ti - (ti * (ti - 1)) / 2);

    if (t == 0) flg = 1;
    __syncthreads();
    if (t < N) {
      if (dims[t] != t) atomicAnd(&flg, 0);
    }
    __syncthreads();
    int contig = flg;

    const float* xb = x + (size_t)b * CH * XD;
    const float* ab = a + (size_t)b * CH * XD;

    if (contig) {
      // coalesced: thread = (ch-pair cp = t>>2, dim-quad dq = t&3)
      int dq = t & 3, cpl = t >> 2;  // cpl in 0..63
#pragma unroll
      for (int s = 0; s < 4; ++s) {
        const float* src = (s & 1) ? ab : xb;
        int d0 = ((s & 2) ? tj : ti) * 16 + 4 * dq;
        unsigned(*dst)[PADU] = (s & 2) ? ((s & 1) ? sAj : sXj)
                                       : ((s & 1) ? sAi : sXi);
#pragma unroll
        for (int h = 0; h < 2; ++h) {
          int cp = cpl + (h << 6);  // channel-pair 0..127
          float4 f0 = *(const float4*)&src[(size_t)(2 * cp) * XD + d0];
          float4 f1 = *(const float4*)&src[(size_t)(2 * cp + 1) * XD + d0];
          dst[4 * dq + 0][cp] = h2u(__builtin_amdgcn_cvt_pkrtz(f0.x, f1.x));
          dst[4 * dq + 1][cp] = h2u(__builtin_amdgcn_cvt_pkrtz(f0.y, f1.y));
          dst[4 * dq + 2][cp] = h2u(__builtin_amdgcn_cvt_pkrtz(f0.z, f1.z));
          dst[4 * dq + 3][cp] = h2u(__builtin_amdgcn_cvt_pkrtz(f0.w, f1.w));
        }
      }
    } else {
      // general gather (arbitrary dims): R16's proven path
      int d16 = t & 15, grp = t >> 4;
      int di = dims[ti * 16 + d16];
      int dj = dims[tj * 16 + d16];
      int c0 = grp * 16;
#pragma unroll
      for (int s = 0; s < 4; ++s) {
        const float* src = (s & 1) ? ab : xb;
        int d = (s & 2) ? dj : di;
        unsigned pk[8];
#pragma unroll
        for (int k = 0; k < 8; ++k) {
          float f0 = src[(size_t)(c0 + 2 * k) * XD + d];
          float f1 = src[(size_t)(c0 + 2 * k + 1) * XD + d];
          pk[k] = h2u(__builtin_amdgcn_cvt_pkrtz(f0, f1));
        }
        unsigned* dst = (s & 2) ? ((s & 1) ? &sAj[d16][0] : &sXj[d16][0])
                                : ((s & 1) ? &sAi[d16][0] : &sXi[d16][0]);
        *(uint4*)&dst[grp * 8] = make_uint4(pk[0], pk[1], pk[2], pk[3]);
        *(uint4*)&dst[grp * 8 + 4] = make_uint4(pk[4], pk[5], pk[6], pk[7]);
      }
    }
    __syncthreads();

    int ii = t >> 4, jj = t & 15;
    float accx = 0.f, accv = 0.f;
#pragma unroll 8
    for (int cq = 0; cq < 32; ++cq) {
      uint4 xi = *(const uint4*)&sXi[ii][cq * 4];
      uint4 xj = *(const uint4*)&sXj[jj][cq * 4];
      uint4 ai = *(const uint4*)&sAi[ii][cq * 4];
      uint4 aj = *(const uint4*)&sAj[jj][cq * 4];
      h2v d0 = u2h(xi.x) - u2h(xj.x);
      accx = __builtin_amdgcn_fdot2(d0, d0, accx, false);
      h2v d1 = u2h(xi.y) - u2h(xj.y);
      accx = __builtin_amdgcn_fdot2(d1, d1, accx, false);
      h2v d2 = u2h(xi.z) - u2h(xj.z);
      accx = __builtin_amdgcn_fdot2(d2, d2, accx, false);
      h2v d3 = u2h(xi.w) - u2h(xj.w);
      accx = __builtin_amdgcn_fdot2(d3, d3, accx, false);
      h2v e0 = u2h(ai.x) - u2h(aj.x);
      accv = __builtin_amdgcn_fdot2(e0, e0, accv, false);
      h2v e1 = u2h(ai.y) - u2h(aj.y);
      accv = __builtin_amdgcn_fdot2(e1, e1, accv, false);
      h2v e2 = u2h(ai.z) - u2h(aj.z);
      accv = __builtin_amdgcn_fdot2(e2, e2, accv, false);
      h2v e3 = u2h(ai.w) - u2h(aj.w);
      accv = __builtin_amdgcn_fdot2(e3, e3, accv, false);
    }
    float vr = sqrtf(accv);
    float mv = vr * expf(-sqrtf(accx));
    int i = ti * 16 + ii, j = tj * 16 + jj;
    vrS[((size_t)b * N + i) * N + j] = vr;
    mS[((size_t)b * N + i) * N + j] = mv;

    float wv = vr, wm = mv;
#pragma unroll
    for (int off = 32; off; off >>= 1) {
      wv = fmaxf(wv, __shfl_xor(wv, off));
      wm = fmaxf(wm, __shfl_xor(wm, off));
    }
    int wid = t >> 6;
    if ((t & 63) == 0) { wred[wid] = wv; wred[8 + wid] = wm; }
    __syncthreads();
    if (t == 0) {
      pmaxV[b * NTILE + tt] = fmaxf(fmaxf(wred[0], wred[1]), fmaxf(wred[2], wred[3]));
      pmaxM[b * NTILE + tt] = fmaxf(fmaxf(wred[8], wred[9]), fmaxf(wred[10], wred[11]));
    }
  } else {
    // ---------------- passthrough role ----------------
    int pb = bid - BS * NTILE;  // 0..NPASS-1
    if (t < XD / 32) inset[t] = 0u;
    __syncthreads();
    if (t < N) atomicOr(&inset[dims[t] >> 5], 1u << (dims[t] & 31));
    __syncthreads();
    int r0 = (pb * (BS * CH)) / NPASS;
    int r1 = ((pb + 1) * (BS * CH)) / NPASS;
    for (int row = r0; row < r1; ++row) {
      const float4* x4 = (const float4*)(x + (size_t)row * XD);
      const float4* a4 = (const float4*)(a + (size_t)row * XD);
      float4* o4 = (float4*)(out + (size_t)row * XD);
      int e = t;  // float4 index 0..255
      unsigned nib = (inset[e >> 3] >> ((e & 7) * 4)) & 0xFu;
      float4 xv = x4[e], av = a4[e];
      float4 o;
      o.x = fmaf((nib & 1u) ? 0.5f : 1.0f, av.x, xv.x);
      o.y = fmaf((nib & 2u) ? 0.5f : 1.0f, av.y, xv.y);
      o.z = fmaf((nib & 4u) ? 0.5f : 1.0f, av.z, xv.z);
      o.w = fmaf((nib & 8u) ? 0.5f : 1.0f, av.w, xv.w);
      o4[e] = o;
    }
  }
}

// ---------------------------------------------------------------------------
// K2: conditional fixup. 32 blocks (8 c-groups x 4 batches) x 256 threads.
// Reduce the 36 per-tile maxes; if the collision mask is empty (always, for
// this data) exit immediately -- k1's passthrough already wrote the exact
// fast path. Otherwise recompute the masked update for this block's 32
// channels, reading the symmetric vrS/mS through a (min,max) index swap.
// ---------------------------------------------------------------------------
__global__ __launch_bounds__(256) void k2_fixup(
    const float* __restrict__ x, const float* __restrict__ a,
    const float* __restrict__ ru, const int* __restrict__ dims,
    const float* __restrict__ vrS, const float* __restrict__ mS,
    const float* __restrict__ pmaxV, const float* __restrict__ pmaxM,
    float* __restrict__ out) {
  int cg = blockIdx.x, b = blockIdx.y;
  int t = threadIdx.x;
  __shared__ float mx2[2];
  __shared__ float xx[N], vv[N];
  __shared__ int dsh[N];

  if (t < 64) {
    float pv = (t < NTILE) ? pmaxV[b * NTILE + t] : 0.f;
    float pm = (t < NTILE) ? pmaxM[b * NTILE + t] : 0.f;
#pragma unroll
    for (int off = 32; off; off >>= 1) {
      pv = fmaxf(pv, __shfl_xor(pv, off));
      pm = fmaxf(pm, __shfl_xor(pm, off));
    }
    if (t == 0) { mx2[0] = pv; mx2[1] = pm; }
  }
  __syncthreads();
  float vrmax = mx2[0], mmax = mx2[1];
  float inv = vrmax > 0.f ? 1.f / vrmax : 0.f;  // vrmax==0 -> all-false mask
  if (!(mmax * inv > 0.5f)) return;  // mask empty: fast path already exact

  // ---- slow path (general correctness; not taken for this input) ----
  if (t < N) dsh[t] = dims[t];
  for (int cc = 0; cc < 32; ++cc) {
    int c = (cg << 5) + cc;
    int bc = (b << 8) + c;
    __syncthreads();
    if (t < N) {
      int d = dsh[t];
      xx[t] = x[(size_t)bc * XD + d];
      vv[t] = a[(size_t)bc * XD + d];
    }
    __syncthreads();
    if (t < N) {
      int j = t;
      const float* rub = ru + (size_t)bc * NP;
      float S = 0.f, sumV = 0.f, sumX = 0.f, R = 0.f;
      for (int i = 0; i < N; ++i) {
        int lo = i < j ? i : j, hi = i < j ? j : i;  // symmetric upper storage
        size_t idx = ((size_t)b * N + lo) * N + hi;
        float mvv = mS[idx];
        if (mvv * inv > 0.5f) {
          S += 1.f;
          sumV += vv[i];
          sumX += xx[i];
          float vrv = vrS[idx];
          int p;
          float sgn;
          if (i < j) {
            p = i * N - ((i * (i + 1)) >> 1) + (j - i - 1);
            sgn = 1.f;
          } else {
            p = j * N - ((j * (j + 1)) >> 1) + (i - j - 1);
            sgn = -1.f;
          }
          R += sgn * TWO_PI_F * vrv * rub[p];
        }
      }
      float vj = vv[j];
      float v_new = vj + 0.5f * S * vj - 0.5f * sumV + R;
      float x_new = 0.5f * xx[j] + 0.5f * (xx[j] + sumX) / (S + 1.f) + 0.5f * v_new;
      out[(size_t)bc * XD + dsh[j]] = x_new;
    }
  }
}

extern "C" void kernel_launch(void* const* d_in, const int* in_sizes, int n_in,
                              void* d_out, int out_size, void* d_ws, size_t ws_size,
                              hipStream_t stream) {
  const float* x = (const float*)d_in[0];
  // d_in[1] = v : unused by the reference computation
  const float* a = (const float*)d_in[2];
  const float* ru = (const float*)d_in[3];
  const int* dims = (const int*)d_in[4];
  float* out = (float*)d_out;

  float* vrS = (float*)d_ws;               // BS*N*N f32 (upper tiles only)
  float* mS = vrS + (size_t)BS * N * N;    // BS*N*N f32 (upper tiles only)
  float* pmaxV = mS + (size_t)BS * N * N;  // BS*NTILE f32
  float* pmaxM = pmaxV + BS * NTILE;       // BS*NTILE f32

  k1_pair_pass<<<BS * NTILE + NPASS, 256, 0, stream>>>(x, a, dims, vrS, mS,
                                                       pmaxV, pmaxM, out);
  k2_fixup<<<dim3(8, BS), 256, 0, stream>>>(x, a, ru, dims, vrS, mS, pmaxV,
                                            pmaxM, out);
}